// Round 12
// baseline (331.474 us; speedup 1.0000x reference)
//
#include <hip/hip_runtime.h>

// ---------------- problem constants ----------------
#define NVEC  131072      // 32*4096 vectors
#define DIM   64
#define K     512
#define DECAYF 0.99f
#define OMDF   0.01f
#define EPSF   1e-5f
#define VPB   128                 // vectors per block: 64 lanes x 2 vectors
#define NBLK_ASSIGN (NVEC / VPB)  // 1024 blocks, 4 waves each

// ---------------- output layout (floats, concatenated in return order) ----
#define Q_OFF    0
#define DIFF_OFF 8388608
#define IND_OFF  8388609
#define NE_OFF   8519681
#define NCS_OFF  8552449
#define NEA_OFF  8552961

// ---------------- ws layout (floats) ----
#define ET_OFF    0        // E^T : K x DIM
#define C_OFF     32768    // np-order sum(E*E, axis=0) : K
#define DPART_OFF 33280    // per-assign-block diff partials : 1024
#define PCNT_OFF  166400   // atomic count accum : K          (zeroed by prep)
#define PESUM_OFF 166912   // atomic esum accum  : K x DIM    (zeroed by prep)
#define STATZ_N   (K + K * DIM)   // 33280 floats to zero
// end: 199680 floats (well under the known-safe 1.33 MB)

// ============ prep: transpose embed -> E^T, C_j; zero atomic stats =======
// Blocks 0-1: transpose (proven body). Blocks 2-131: zero the pcnt/pesum
// atomic-accumulation region (33280 floats = 130 x 256). Runs every launch
// (stream-ordered before assign's atomics) — no memset API needed.
__global__ __launch_bounds__(256) void vq_prep(const float* __restrict__ embed,
                                               float* __restrict__ ws) {
    #pragma clang fp contract(off)
    int bid = blockIdx.x;
    if (bid < 2) {
        int j = bid * 256 + threadIdx.x;
        float c = 0.0f;
        for (int d = 0; d < DIM; ++d) {
            float v = embed[d * K + j];           // coalesced across j
            ws[ET_OFF + j * DIM + d] = v;
            float t = v * v;
            c = c + t;
        }
        ws[C_OFF + j] = c;
    } else {
        int i = (bid - 2) * 256 + threadIdx.x;    // 0..33279
        ws[PCNT_OFF + i] = 0.0f;                  // pcnt then pesum (contiguous)
    }
}

// ============ main: np-fp32-replica argmin + fused atomic stats ==========
// Assign core is R9/R11-exact (best measured: 163-168 µs; SMEM e-stream,
// R=2 dual-chain, wpe(3)). Design-space verdicts (measured): VMEM e-path
// dead (R2 592 / R10 973 µs), LDS broadcast dead (R3 254 µs), SMEM+R=1
// inflates VALU 2.4x (R1), more-ILP/fewer-waves configs all >= 200 µs.
// NEW THIS ROUND: the previously-idle waves 2,3 compute the histogram +
// segment-sum via fire-and-forget global atomics (device-scope, m20),
// deleting the entire vq_stats kernel + its launch gap + indI traffic.
// Numerics: pcnt sums of 1.0f are exact integers in any order -> ncs, n,
// csz BIT-IDENTICAL. diff path untouched (waves 2,3 still contribute 0 to
// dpart). Only pesum's summation order changes: ~1e-7 on new_embed_avg,
// far under tolerance. Indices and quantize outputs untouched.
__global__ __launch_bounds__(256)
__attribute__((amdgpu_waves_per_eu(3)))
void vq_assign(
    const float* __restrict__ x,
    const float* __restrict__ ET,      // ws + ET_OFF
    const float* __restrict__ C,       // ws + C_OFF
    float* __restrict__ pcnt,          // ws + PCNT_OFF  (atomic)
    float* __restrict__ pesum,         // ws + PESUM_OFF (atomic)
    float* __restrict__ dpart,         // ws + DPART_OFF
    float* __restrict__ out)
{
    #pragma clang fp contract(off)
    __shared__ float sda[4][64], sdb[4][64];
    __shared__ int   sia[4][64], sib[4][64];
    __shared__ int   sba[64], sbb[64];
    __shared__ float wdl[4];

    int lane = threadIdx.x & 63;
    int wq   = __builtin_amdgcn_readfirstlane(threadIdx.x >> 6); // 0..3
    int va   = blockIdx.x * VPB + lane;
    int vb   = va + 64;
    const float* fxa = x + (size_t)va * DIM;
    const float* fxb = x + (size_t)vb * DIM;

    float fa[DIM], fb[DIM];
    #pragma unroll
    for (int k = 0; k < DIM / 4; ++k) {
        float4 t = ((const float4*)fxa)[k];
        fa[4*k+0] = t.x; fa[4*k+1] = t.y; fa[4*k+2] = t.z; fa[4*k+3] = t.w;
    }
    #pragma unroll
    for (int k = 0; k < DIM / 4; ++k) {
        float4 t = ((const float4*)fxb)[k];
        fb[4*k+0] = t.x; fb[4*k+1] = t.y; fb[4*k+2] = t.z; fb[4*k+3] = t.w;
    }

    // Pin fa/fb in VGPRs (identity asm: values defined by asm can't be
    // rematerialized from memory).
    #define PIN16(a, b) asm volatile("" \
        : "+v"(a[(b)+0]),  "+v"(a[(b)+1]),  "+v"(a[(b)+2]),  "+v"(a[(b)+3]), \
          "+v"(a[(b)+4]),  "+v"(a[(b)+5]),  "+v"(a[(b)+6]),  "+v"(a[(b)+7]), \
          "+v"(a[(b)+8]),  "+v"(a[(b)+9]),  "+v"(a[(b)+10]), "+v"(a[(b)+11]), \
          "+v"(a[(b)+12]), "+v"(a[(b)+13]), "+v"(a[(b)+14]), "+v"(a[(b)+15]))
    PIN16(fa, 0); PIN16(fa, 16); PIN16(fa, 32); PIN16(fa, 48);
    PIN16(fb, 0); PIN16(fb, 16); PIN16(fb, 32); PIN16(fb, 48);
    #undef PIN16

    // A per vector: numpy pairwise, n=64 -> 8 accumulators stride 8, then
    // ((r0+r1)+(r2+r3))+((r4+r5)+(r6+r7)). Plain mul+add (contract off).
    float ra[8], rb[8];
    #pragma unroll
    for (int k = 0; k < 8; ++k) { ra[k] = fa[k] * fa[k]; rb[k] = fb[k] * fb[k]; }
    #pragma unroll
    for (int b = 1; b < 8; ++b) {
        #pragma unroll
        for (int k = 0; k < 8; ++k) {
            float t0 = fa[8*b + k] * fa[8*b + k];
            ra[k] = ra[k] + t0;
            float t1 = fb[8*b + k] * fb[8*b + k];
            rb[k] = rb[k] + t1;
        }
    }
    float Aa = ((ra[0] + ra[1]) + (ra[2] + ra[3])) + ((ra[4] + ra[5]) + (ra[6] + ra[7]));
    float Ab = ((rb[0] + rb[1]) + (rb[2] + rb[3])) + ((rb[4] + rb[5]) + (rb[6] + rb[7]));

    // wave-uniform code segment -> s_load e-stream; one scalar feeds 2 FMAs.
    const float* eseg = ET + (size_t)wq * 128 * DIM;
    const float* Cseg = C + wq * 128;
    float bda = 3.0e38f, bdb = 3.0e38f;
    int   bia = wq * 128, bib = wq * 128;
    #pragma unroll 1
    for (int jj = 0; jj < 128; ++jj) {
        const float* e = eseg + jj * DIM;
        float ma = 0.0f, mb = 0.0f;
        #pragma unroll
        for (int d = 0; d < DIM; ++d) {
            float ev = e[d];
            ma = __builtin_fmaf(fa[d], ev, ma);
            mb = __builtin_fmaf(fb[d], ev, mb);
        }
        int j = wq * 128 + jj;
        float Cv = Cseg[jj];
        float t1a = 2.0f * ma;           // exact (x2)
        float t2a = Aa - t1a;            // rounded
        float da  = t2a + Cv;            // rounded
        float t1b = 2.0f * mb;
        float t2b = Ab - t1b;
        float db  = t2b + Cv;
        if (da < bda) { bda = da; bia = j; }
        if (db < bdb) { bdb = db; bib = j; }
    }

    sda[wq][lane] = bda; sia[wq][lane] = bia;
    sdb[wq][lane] = bdb; sib[wq][lane] = bib;
    __syncthreads();

    if (wq == 0) {
        // 4-way merge, ascending q, tie -> smaller index: numpy first-min.
        float bd = sda[0][lane]; int bi = sia[0][lane];
        #pragma unroll
        for (int q = 1; q < 4; ++q) {
            float d2 = sda[q][lane]; int i2 = sia[q][lane];
            if (d2 < bd || (d2 == bd && i2 < bi)) { bd = d2; bi = i2; }
        }
        sba[lane] = bi;
        out[IND_OFF + va] = (float)bi;   // coalesced

        bd = sdb[0][lane]; bi = sib[0][lane];
        #pragma unroll
        for (int q = 1; q < 4; ++q) {
            float d2 = sdb[q][lane]; int i2 = sib[q][lane];
            if (d2 < bd || (d2 == bd && i2 < bi)) { bd = d2; bi = i2; }
        }
        sbb[lane] = bi;
        out[IND_OFF + vb] = (float)bi;
    }
    __syncthreads();

    // epilogue: wave0 -> quantize+diff for va (vs pinned fa), wave1 -> vb
    // (vs fb); wave2 -> atomic stats for va set; wave3 -> vb set.
    // Waves 2,3 keep dl = 0 so dpart stays exactly wdl[0]+wdl[1].
    float dl = 0.0f;
    if (wq == 0) {
        int bsel = sba[lane];
        const float4* qr = (const float4*)(ET + (size_t)bsel * DIM);
        float4* orow = (float4*)(out + Q_OFF + (size_t)va * DIM);
        #pragma unroll
        for (int k = 0; k < 16; ++k) {
            float4 tq = qr[k];
            float r0 = tq.x - fa[4*k+0];
            float r1 = tq.y - fa[4*k+1];
            float r2 = tq.z - fa[4*k+2];
            float r3 = tq.w - fa[4*k+3];
            dl = __builtin_fmaf(r0, r0, dl); dl = __builtin_fmaf(r1, r1, dl);
            dl = __builtin_fmaf(r2, r2, dl); dl = __builtin_fmaf(r3, r3, dl);
            orow[k] = tq;
        }
    } else if (wq == 1) {
        int bsel = sbb[lane];
        const float4* qr = (const float4*)(ET + (size_t)bsel * DIM);
        float4* orow = (float4*)(out + Q_OFF + (size_t)vb * DIM);
        #pragma unroll
        for (int k = 0; k < 16; ++k) {
            float4 tq = qr[k];
            float r0 = tq.x - fb[4*k+0];
            float r1 = tq.y - fb[4*k+1];
            float r2 = tq.z - fb[4*k+2];
            float r3 = tq.w - fb[4*k+3];
            dl = __builtin_fmaf(r0, r0, dl); dl = __builtin_fmaf(r1, r1, dl);
            dl = __builtin_fmaf(r2, r2, dl); dl = __builtin_fmaf(r3, r3, dl);
            orow[k] = tq;
        }
    } else if (wq == 2) {
        // counts: lane-parallel (HW serializes same-address lanes; exact ints)
        atomicAdd(&pcnt[sba[lane]], 1.0f);
        // row sums: fire-and-forget atomics pipeline at issue rate
        int base = blockIdx.x * VPB;
        #pragma unroll 4
        for (int k = 0; k < 64; ++k) {
            int bi = sba[k];                       // LDS broadcast
            const float* xr = x + (size_t)(base + k) * DIM;
            atomicAdd(&pesum[(size_t)bi * DIM + lane], xr[lane]);
        }
    } else {
        atomicAdd(&pcnt[sbb[lane]], 1.0f);
        int base = blockIdx.x * VPB + 64;
        #pragma unroll 4
        for (int k = 0; k < 64; ++k) {
            int bi = sbb[k];
            const float* xr = x + (size_t)(base + k) * DIM;
            atomicAdd(&pesum[(size_t)bi * DIM + lane], xr[lane]);
        }
    }

    #pragma unroll
    for (int off = 32; off > 0; off >>= 1) dl += __shfl_down(dl, off);
    if (lane == 0) wdl[wq] = dl;
    __syncthreads();
    if (threadIdx.x == 0)
        dpart[blockIdx.x] = ((wdl[0] + wdl[1]) + (wdl[2] + wdl[3]));
}

// ============ finalize (merged): 64 blocks, one per d ====================
// Each block recomputes ncs[j] and n with the EXACT op sequence of the
// proven finalize (cj is now the single atomic count — an exact integer
// equal bit-for-bit to the old 4-partial sum; same shuffle tree) -> n is
// bit-identical in every block. Block 0 additionally writes ncs, diff.
__global__ __launch_bounds__(512) void vq_finalize(
    const float* __restrict__ cluster_size,
    const float* __restrict__ embed_avg,
    const float* __restrict__ ws,
    float* __restrict__ out)
{
    __shared__ float wsum[8];
    __shared__ float dsum_sh[8];
    __shared__ float n_sh;
    int d = blockIdx.x;     // 0..63
    int j = threadIdx.x;    // 0..511

    float cj = ws[PCNT_OFF + j];        // exact integer (atomic 1.0f sums)
    float ncs = DECAYF * cluster_size[j] + OMDF * cj;
    if (d == 0) out[NCS_OFF + j] = ncs;

    // diff partial sum only needed in block 0 (d uniform per block)
    float dsum = 0.0f;
    if (d == 0) {
        #pragma unroll
        for (int k = 0; k < NBLK_ASSIGN / 512; ++k)
            dsum += ws[DPART_OFF + k * 512 + j];
    }

    float s = ncs;
    #pragma unroll
    for (int off = 32; off > 0; off >>= 1) {
        s    += __shfl_down(s, off);
        dsum += __shfl_down(dsum, off);
    }
    if ((j & 63) == 0) { wsum[j >> 6] = s; dsum_sh[j >> 6] = dsum; }
    __syncthreads();
    if (j == 0) {
        float n = 0.f, dtot = 0.f;
        #pragma unroll
        for (int w = 0; w < 8; ++w) { n += wsum[w]; dtot += dsum_sh[w]; }
        n_sh = n;
        if (d == 0) out[DIFF_OFF] = dtot * (1.0f / 8388608.0f);  // 2^23: exact
    }
    __syncthreads();
    float n   = n_sh;
    float csz = (ncs + EPSF) / (n + (float)K * EPSF) * n;

    float es = ws[PESUM_OFF + (size_t)j * DIM + d];   // atomic-accumulated
    float ea = DECAYF * embed_avg[d * K + j] + OMDF * es;
    out[NEA_OFF + d * K + j] = ea;        // coalesced over j
    out[NE_OFF  + d * K + j] = ea / csz;
}

// ============ launch ============
extern "C" void kernel_launch(void* const* d_in, const int* in_sizes, int n_in,
                              void* d_out, int out_size, void* d_ws, size_t ws_size,
                              hipStream_t stream) {
    const float* x            = (const float*)d_in[0];
    const float* embed        = (const float*)d_in[1];
    const float* cluster_size = (const float*)d_in[2];
    const float* embed_avg    = (const float*)d_in[3];
    float* out = (float*)d_out;
    float* ws  = (float*)d_ws;

    vq_prep<<<2 + STATZ_N / 256, 256, 0, stream>>>(embed, ws);
    vq_assign<<<NBLK_ASSIGN, 256, 0, stream>>>(
        x, ws + ET_OFF, ws + C_OFF, ws + PCNT_OFF, ws + PESUM_OFF,
        ws + DPART_OFF, out);
    vq_finalize<<<DIM, K, 0, stream>>>(cluster_size, embed_avg, ws, out);
}